// Round 10
// baseline (71.595 us; speedup 1.0000x reference)
//
#include <hip/hip_runtime.h>

#define B_ 16
#define QN 256
#define KN 256
#define DN 256
#define HN 256

#define LOG2E 1.4426950408889634f
#define TWOLOG2E 2.8853900817779268f  // exp2(x*this) = e^{2x}

__device__ inline float readlane_f(float v, int l) {
    return __uint_as_float(__builtin_amdgcn_readlane(__float_as_uint(v), l));
}

// ---------------- Kernel A (fused): projections + exp ----------------
// 16 rows/block; thread = 4 rows x 4 h. Outputs are EXPONENTIALS of the scaled
// projections: eq = exp2(s*q@Wq), ek = exp2(s*k@Wk), s = 2*log2(e), so the score
// kernel needs no exp (e^{2(q+k)} = eq*ek).
// q-path: row-major direct stores. k-path: LDS transpose into [h/8][k][8] octet
// layout so the score kernel's window loads are 2x b128 per 8 h.
__global__ __launch_bounds__(256) void proj_kernel(const float* __restrict__ Xq,
                                                   const float* __restrict__ Xk,
                                                   const float* __restrict__ Wq,
                                                   const float* __restrict__ Wk,
                                                   float* __restrict__ EQ,
                                                   float* __restrict__ EKT,
                                                   float scale) {
    const int nb = (int)gridDim.x >> 1;
    int blk = blockIdx.x;
    const bool is_q = blk < nb;
    const float* X;
    const float* W;
    if (is_q) { X = Xq; W = Wq; }
    else      { X = Xk; W = Wk; blk -= nb; }
    const int row0 = blk * 16;

    __shared__ float xl[16][260];
    __shared__ float trans[16][260];
    const int tid = threadIdx.x;

    {
        const float4* src = (const float4*)(X + (size_t)row0 * DN);
#pragma unroll
        for (int i = 0; i < 4; ++i) {
            int idx = tid + 256 * i;
            int r = idx >> 6, c = (idx & 63) << 2;
            *(float4*)&xl[r][c] = src[idx];
        }
    }
    __syncthreads();

    const int rg = tid >> 6;          // wave id: rows rg*4 .. rg*4+3
    const int h4 = (tid & 63) << 2;   // 4 h columns

    float4 acc[4];
#pragma unroll
    for (int r = 0; r < 4; ++r) acc[r] = make_float4(0.f, 0.f, 0.f, 0.f);

    float4 wb0[4], wb1[4];
#pragma unroll
    for (int j = 0; j < 4; ++j) wb0[j] = *(const float4*)&W[(size_t)j * HN + h4];

#define PROJ_COMP(WB, D0)                                                      \
    do {                                                                       \
        float4 x[4];                                                           \
        _Pragma("unroll") for (int r = 0; r < 4; ++r)                          \
            x[r] = *(const float4*)&xl[(rg << 2) + r][(D0)];                   \
        _Pragma("unroll") for (int r = 0; r < 4; ++r) {                        \
            acc[r].x = fmaf(x[r].x, WB[0].x, acc[r].x);                        \
            acc[r].y = fmaf(x[r].x, WB[0].y, acc[r].y);                        \
            acc[r].z = fmaf(x[r].x, WB[0].z, acc[r].z);                        \
            acc[r].w = fmaf(x[r].x, WB[0].w, acc[r].w);                        \
            acc[r].x = fmaf(x[r].y, WB[1].x, acc[r].x);                        \
            acc[r].y = fmaf(x[r].y, WB[1].y, acc[r].y);                        \
            acc[r].z = fmaf(x[r].y, WB[1].z, acc[r].z);                        \
            acc[r].w = fmaf(x[r].y, WB[1].w, acc[r].w);                        \
            acc[r].x = fmaf(x[r].z, WB[2].x, acc[r].x);                        \
            acc[r].y = fmaf(x[r].z, WB[2].y, acc[r].y);                        \
            acc[r].z = fmaf(x[r].z, WB[2].z, acc[r].z);                        \
            acc[r].w = fmaf(x[r].z, WB[2].w, acc[r].w);                        \
            acc[r].x = fmaf(x[r].w, WB[3].x, acc[r].x);                        \
            acc[r].y = fmaf(x[r].w, WB[3].y, acc[r].y);                        \
            acc[r].z = fmaf(x[r].w, WB[3].z, acc[r].z);                        \
            acc[r].w = fmaf(x[r].w, WB[3].w, acc[r].w);                        \
        }                                                                      \
    } while (0)

    for (int d0 = 0; d0 < DN; d0 += 8) {
#pragma unroll
        for (int j = 0; j < 4; ++j)
            wb1[j] = *(const float4*)&W[(size_t)(d0 + 4 + j) * HN + h4];
        PROJ_COMP(wb0, d0);
        if (d0 + 8 < DN) {
#pragma unroll
            for (int j = 0; j < 4; ++j)
                wb0[j] = *(const float4*)&W[(size_t)(d0 + 8 + j) * HN + h4];
        }
        PROJ_COMP(wb1, d0 + 4);
    }

    // apply exp2(scale * acc)
#pragma unroll
    for (int r = 0; r < 4; ++r) {
        acc[r].x = __builtin_amdgcn_exp2f(acc[r].x * scale);
        acc[r].y = __builtin_amdgcn_exp2f(acc[r].y * scale);
        acc[r].z = __builtin_amdgcn_exp2f(acc[r].z * scale);
        acc[r].w = __builtin_amdgcn_exp2f(acc[r].w * scale);
    }

    if (is_q) {
#pragma unroll
        for (int r = 0; r < 4; ++r)
            *(float4*)&EQ[(size_t)(row0 + (rg << 2) + r) * HN + h4] = acc[r];
    } else {
#pragma unroll
        for (int r = 0; r < 4; ++r)
            *(float4*)&trans[(rg << 2) + r][h4] = acc[r];
        __syncthreads();
        const int b = row0 >> 8, kloc0 = row0 & 255;
        float* dstb = EKT + (size_t)b * 32 * 256 * 8;
        // [h0][k][u] layout, coalesced stores
#pragma unroll
        for (int i = 0; i < 4; ++i) {
            int idx = i * 256 + tid;          // float4 index, 0..1023
            int u4 = (idx & 1) << 2;
            int kj = (idx >> 1) & 15;
            int h0 = idx >> 5;                // 0..31
            float4 val = *(const float4*)&trans[kj][h0 * 8 + u4];
            *(float4*)&dstb[((size_t)h0 * 256 + kloc0 + kj) * 8 + u4] = val;
        }
    }
}

// ------------- Kernel B (fused): score + masked softmax + PV ----------------
// Block = 4 waves = 4 q rows. WAVE = ONE K-GROUP (k = 64*w + lane) FOR ALL 4 Q:
// each ek octet is loaded once per block and feeds 4 q (score work per load 4x ->
// trans-bound, not L1-bound). eq/wv via wave-uniform (scalar-path) loads.
// softmax: intra-wave shfl reduce + 16-float LDS cross-wave combine; masked p == 0.
// PV: wave reads only ITS 64 V rows (clamped to len), partial O in registers,
// combined via 16 KB LDS reduce.
__global__ __launch_bounds__(256, 4) void attn_kernel(const float* __restrict__ EQ,
                                                      const float* __restrict__ EKT,
                                                      const float* __restrict__ wv,
                                                      const int* __restrict__ lens,
                                                      const float* __restrict__ V,
                                                      float* __restrict__ OUT) {
    const int b = blockIdx.y;
    const int q0 = blockIdx.x * 4;
    const int len = lens[b];

    __shared__ float part[4][4][256];   // 16 KB: [wave][q][d]
    __shared__ float maxb[4][4];        // [wave][q]
    __shared__ float sumb[4][4];

    const int tid = threadIdx.x;
    const int w = tid >> 6, lane = tid & 63;
    const bool act = (w * 64) < len;          // wave-uniform

    const float* ekb = EKT + (size_t)b * 32 * 256 * 8;
    const float* qr0 = EQ + ((size_t)b * QN + q0 + 0) * HN;   // uniform pointers
    const float* qr1 = EQ + ((size_t)b * QN + q0 + 1) * HN;
    const float* qr2 = EQ + ((size_t)b * QN + q0 + 2) * HN;
    const float* qr3 = EQ + ((size_t)b * QN + q0 + 3) * HN;

    float a0 = 0.f, a1 = 0.f, a2 = 0.f, a3 = 0.f;

    if (act) {
        const float* kp = ekb + (size_t)(w * 64 + lane) * 8;
#pragma unroll 4
        for (int hw = 0; hw < 32; ++hw) {
            const float* kpw = kp + (size_t)hw * 2048;
            float4 ka = *(const float4*)&kpw[0];
            float4 kb = *(const float4*)&kpw[4];
            const int h8 = hw * 8;
            float4 wa = *(const float4*)&wv[h8];
            float4 wb = *(const float4*)&wv[h8 + 4];
#define Q_TERMS(ACC, QR)                                                          \
    do {                                                                          \
        float4 qa = *(const float4*)&QR[h8];                                      \
        float4 qb = *(const float4*)&QR[h8 + 4];                                  \
        ACC = fmaf(wa.x, __builtin_amdgcn_rcpf(fmaf(qa.x, ka.x, 1.f)), ACC);      \
        ACC = fmaf(wa.y, __builtin_amdgcn_rcpf(fmaf(qa.y, ka.y, 1.f)), ACC);      \
        ACC = fmaf(wa.z, __builtin_amdgcn_rcpf(fmaf(qa.z, ka.z, 1.f)), ACC);      \
        ACC = fmaf(wa.w, __builtin_amdgcn_rcpf(fmaf(qa.w, ka.w, 1.f)), ACC);      \
        ACC = fmaf(wb.x, __builtin_amdgcn_rcpf(fmaf(qb.x, kb.x, 1.f)), ACC);      \
        ACC = fmaf(wb.y, __builtin_amdgcn_rcpf(fmaf(qb.y, kb.y, 1.f)), ACC);      \
        ACC = fmaf(wb.z, __builtin_amdgcn_rcpf(fmaf(qb.z, kb.z, 1.f)), ACC);      \
        ACC = fmaf(wb.w, __builtin_amdgcn_rcpf(fmaf(qb.w, kb.w, 1.f)), ACC);      \
    } while (0)
            Q_TERMS(a0, qr0);
            Q_TERMS(a1, qr1);
            Q_TERMS(a2, qr2);
            Q_TERMS(a3, qr3);
        }
    }

    const bool kvalid = (w * 64 + lane) < len;
    float xs0 = kvalid ? (-2.f * a0) : -1e6f;
    float xs1 = kvalid ? (-2.f * a1) : -1e6f;
    float xs2 = kvalid ? (-2.f * a2) : -1e6f;
    float xs3 = kvalid ? (-2.f * a3) : -1e6f;

    // intra-wave max per q
    float m0 = xs0, m1 = xs1, m2 = xs2, m3 = xs3;
#pragma unroll
    for (int off = 32; off; off >>= 1) {
        m0 = fmaxf(m0, __shfl_xor(m0, off, 64));
        m1 = fmaxf(m1, __shfl_xor(m1, off, 64));
        m2 = fmaxf(m2, __shfl_xor(m2, off, 64));
        m3 = fmaxf(m3, __shfl_xor(m3, off, 64));
    }
    if (lane == 0) {
        maxb[w][0] = m0; maxb[w][1] = m1; maxb[w][2] = m2; maxb[w][3] = m3;
    }
    __syncthreads();
    float g0 = fmaxf(fmaxf(maxb[0][0], maxb[1][0]), fmaxf(maxb[2][0], maxb[3][0]));
    float g1 = fmaxf(fmaxf(maxb[0][1], maxb[1][1]), fmaxf(maxb[2][1], maxb[3][1]));
    float g2 = fmaxf(fmaxf(maxb[0][2], maxb[1][2]), fmaxf(maxb[2][2], maxb[3][2]));
    float g3 = fmaxf(fmaxf(maxb[0][3], maxb[1][3]), fmaxf(maxb[2][3], maxb[3][3]));

    float p0 = __builtin_amdgcn_exp2f((xs0 - g0) * LOG2E);
    float p1 = __builtin_amdgcn_exp2f((xs1 - g1) * LOG2E);
    float p2 = __builtin_amdgcn_exp2f((xs2 - g2) * LOG2E);
    float p3 = __builtin_amdgcn_exp2f((xs3 - g3) * LOG2E);

    float s0 = p0, s1 = p1, s2 = p2, s3 = p3;
#pragma unroll
    for (int off = 32; off; off >>= 1) {
        s0 += __shfl_xor(s0, off, 64);
        s1 += __shfl_xor(s1, off, 64);
        s2 += __shfl_xor(s2, off, 64);
        s3 += __shfl_xor(s3, off, 64);
    }
    if (lane == 0) {
        sumb[w][0] = s0; sumb[w][1] = s1; sumb[w][2] = s2; sumb[w][3] = s3;
    }
    __syncthreads();
    float t0 = (sumb[0][0] + sumb[1][0]) + (sumb[2][0] + sumb[3][0]);
    float t1 = (sumb[0][1] + sumb[1][1]) + (sumb[2][1] + sumb[3][1]);
    float t2 = (sumb[0][2] + sumb[1][2]) + (sumb[2][2] + sumb[3][2]);
    float t3 = (sumb[0][3] + sumb[1][3]) + (sumb[2][3] + sumb[3][3]);
    p0 *= 1.f / t0;
    p1 *= 1.f / t1;
    p2 *= 1.f / t2;
    p3 *= 1.f / t3;

    // PV: wave w covers k rows [64w, min(64w+64, len)); lane covers d = 4*lane..+3
    float4 op0 = make_float4(0.f, 0.f, 0.f, 0.f);
    float4 op1 = op0, op2 = op0, op3 = op0;
    if (act) {
        int kmax = len - w * 64;
        if (kmax > 64) kmax = 64;
        const float* vb = V + ((size_t)b * KN + (size_t)w * 64) * DN;
        const int d4 = lane << 2;
#pragma unroll 4
        for (int kk = 0; kk < kmax; ++kk) {
            float4 v = *(const float4*)&vb[(size_t)kk * DN + d4];
            float b0 = readlane_f(p0, kk);
            float b1 = readlane_f(p1, kk);
            float b2 = readlane_f(p2, kk);
            float b3 = readlane_f(p3, kk);
            op0.x = fmaf(b0, v.x, op0.x); op0.y = fmaf(b0, v.y, op0.y);
            op0.z = fmaf(b0, v.z, op0.z); op0.w = fmaf(b0, v.w, op0.w);
            op1.x = fmaf(b1, v.x, op1.x); op1.y = fmaf(b1, v.y, op1.y);
            op1.z = fmaf(b1, v.z, op1.z); op1.w = fmaf(b1, v.w, op1.w);
            op2.x = fmaf(b2, v.x, op2.x); op2.y = fmaf(b2, v.y, op2.y);
            op2.z = fmaf(b2, v.z, op2.z); op2.w = fmaf(b2, v.w, op2.w);
            op3.x = fmaf(b3, v.x, op3.x); op3.y = fmaf(b3, v.y, op3.y);
            op3.z = fmaf(b3, v.z, op3.z); op3.w = fmaf(b3, v.w, op3.w);
        }
    }
    {
        const int d4 = lane << 2;
        *(float4*)&part[w][0][d4] = op0;
        *(float4*)&part[w][1][d4] = op1;
        *(float4*)&part[w][2][d4] = op2;
        *(float4*)&part[w][3][d4] = op3;
    }
    __syncthreads();

    // cross-wave O reduce: thread (q=tid>>6, ln=tid&63) sums 4 partials
    {
        const int q = tid >> 6, ln = tid & 63;
        const int d4 = ln << 2;
        float4 r0 = *(const float4*)&part[0][q][d4];
        float4 r1 = *(const float4*)&part[1][q][d4];
        float4 r2 = *(const float4*)&part[2][q][d4];
        float4 r3 = *(const float4*)&part[3][q][d4];
        float4 r = make_float4((r0.x + r1.x) + (r2.x + r3.x),
                               (r0.y + r1.y) + (r2.y + r3.y),
                               (r0.z + r1.z) + (r2.z + r3.z),
                               (r0.w + r1.w) + (r2.w + r3.w));
        *(float4*)&OUT[((size_t)b * QN + q0 + q) * DN + d4] = r;
    }
}

extern "C" void kernel_launch(void* const* d_in, const int* in_sizes, int n_in,
                              void* d_out, int out_size, void* d_ws, size_t ws_size,
                              hipStream_t stream) {
    const float* queries = (const float*)d_in[0];
    const float* keys    = (const float*)d_in[1];
    const float* values  = (const float*)d_in[2];
    const int*   lens    = (const int*)d_in[3];
    const float* Wq      = (const float*)d_in[4];
    const float* Wk      = (const float*)d_in[5];
    const float* wv      = (const float*)d_in[6];
    float* out = (float*)d_out;

    float* eq  = (float*)d_ws;                       // [B,Q,H]   4 MB (exp'd, row-major)
    float* ekT = eq + (size_t)B_ * QN * HN;          // [B,32,K,8] 4 MB (exp'd, octets)

    proj_kernel<<<(B_ * QN + B_ * KN) / 16, 256, 0, stream>>>(
        queries, keys, Wq, Wk, eq, ekT, TWOLOG2E);

    dim3 gB(QN / 4, B_);
    attn_kernel<<<gB, 256, 0, stream>>>(eq, ekT, wv, lens, values, out);
}

// Round 11
// 58.591 us; speedup vs baseline: 1.2219x; 1.2219x over previous
//
#include <hip/hip_runtime.h>

#define B_ 16
#define QN 256
#define KN 256
#define DN 256
#define HN 256

#define LOG2E 1.4426950408889634f
#define TWOLOG2E 2.8853900817779268f  // exp2(x*this) = e^{2x}

__device__ inline float readlane_f(float v, int l) {
    return __uint_as_float(__builtin_amdgcn_readlane(__float_as_uint(v), l));
}

// ---------------- Kernel A (fused): projections + exp ----------------
// (unchanged from R10: 16 rows/block, 4r x 4h per thread, W 2-stage pipelined,
//  exp2 applied in epilogue; k-path stored transposed in [h/8][k][8] octets)
__global__ __launch_bounds__(256) void proj_kernel(const float* __restrict__ Xq,
                                                   const float* __restrict__ Xk,
                                                   const float* __restrict__ Wq,
                                                   const float* __restrict__ Wk,
                                                   float* __restrict__ EQ,
                                                   float* __restrict__ EKT,
                                                   float scale) {
    const int nb = (int)gridDim.x >> 1;
    int blk = blockIdx.x;
    const bool is_q = blk < nb;
    const float* X;
    const float* W;
    if (is_q) { X = Xq; W = Wq; }
    else      { X = Xk; W = Wk; blk -= nb; }
    const int row0 = blk * 16;

    __shared__ float xl[16][260];
    __shared__ float trans[16][260];
    const int tid = threadIdx.x;

    {
        const float4* src = (const float4*)(X + (size_t)row0 * DN);
#pragma unroll
        for (int i = 0; i < 4; ++i) {
            int idx = tid + 256 * i;
            int r = idx >> 6, c = (idx & 63) << 2;
            *(float4*)&xl[r][c] = src[idx];
        }
    }
    __syncthreads();

    const int rg = tid >> 6;
    const int h4 = (tid & 63) << 2;

    float4 acc[4];
#pragma unroll
    for (int r = 0; r < 4; ++r) acc[r] = make_float4(0.f, 0.f, 0.f, 0.f);

    float4 wb0[4], wb1[4];
#pragma unroll
    for (int j = 0; j < 4; ++j) wb0[j] = *(const float4*)&W[(size_t)j * HN + h4];

#define PROJ_COMP(WB, D0)                                                      \
    do {                                                                       \
        float4 x[4];                                                           \
        _Pragma("unroll") for (int r = 0; r < 4; ++r)                          \
            x[r] = *(const float4*)&xl[(rg << 2) + r][(D0)];                   \
        _Pragma("unroll") for (int r = 0; r < 4; ++r) {                        \
            acc[r].x = fmaf(x[r].x, WB[0].x, acc[r].x);                        \
            acc[r].y = fmaf(x[r].x, WB[0].y, acc[r].y);                        \
            acc[r].z = fmaf(x[r].x, WB[0].z, acc[r].z);                        \
            acc[r].w = fmaf(x[r].x, WB[0].w, acc[r].w);                        \
            acc[r].x = fmaf(x[r].y, WB[1].x, acc[r].x);                        \
            acc[r].y = fmaf(x[r].y, WB[1].y, acc[r].y);                        \
            acc[r].z = fmaf(x[r].y, WB[1].z, acc[r].z);                        \
            acc[r].w = fmaf(x[r].y, WB[1].w, acc[r].w);                        \
            acc[r].x = fmaf(x[r].z, WB[2].x, acc[r].x);                        \
            acc[r].y = fmaf(x[r].z, WB[2].y, acc[r].y);                        \
            acc[r].z = fmaf(x[r].z, WB[2].z, acc[r].z);                        \
            acc[r].w = fmaf(x[r].z, WB[2].w, acc[r].w);                        \
            acc[r].x = fmaf(x[r].w, WB[3].x, acc[r].x);                        \
            acc[r].y = fmaf(x[r].w, WB[3].y, acc[r].y);                        \
            acc[r].z = fmaf(x[r].w, WB[3].z, acc[r].z);                        \
            acc[r].w = fmaf(x[r].w, WB[3].w, acc[r].w);                        \
        }                                                                      \
    } while (0)

    for (int d0 = 0; d0 < DN; d0 += 8) {
#pragma unroll
        for (int j = 0; j < 4; ++j)
            wb1[j] = *(const float4*)&W[(size_t)(d0 + 4 + j) * HN + h4];
        PROJ_COMP(wb0, d0);
        if (d0 + 8 < DN) {
#pragma unroll
            for (int j = 0; j < 4; ++j)
                wb0[j] = *(const float4*)&W[(size_t)(d0 + 8 + j) * HN + h4];
        }
        PROJ_COMP(wb1, d0 + 4);
    }

#pragma unroll
    for (int r = 0; r < 4; ++r) {
        acc[r].x = __builtin_amdgcn_exp2f(acc[r].x * scale);
        acc[r].y = __builtin_amdgcn_exp2f(acc[r].y * scale);
        acc[r].z = __builtin_amdgcn_exp2f(acc[r].z * scale);
        acc[r].w = __builtin_amdgcn_exp2f(acc[r].w * scale);
    }

    if (is_q) {
#pragma unroll
        for (int r = 0; r < 4; ++r)
            *(float4*)&EQ[(size_t)(row0 + (rg << 2) + r) * HN + h4] = acc[r];
    } else {
#pragma unroll
        for (int r = 0; r < 4; ++r)
            *(float4*)&trans[(rg << 2) + r][h4] = acc[r];
        __syncthreads();
        const int b = row0 >> 8, kloc0 = row0 & 255;
        float* dstb = EKT + (size_t)b * 32 * 256 * 8;
#pragma unroll
        for (int i = 0; i < 4; ++i) {
            int idx = i * 256 + tid;
            int u4 = (idx & 1) << 2;
            int kj = (idx >> 1) & 15;
            int h0 = idx >> 5;
            float4 val = *(const float4*)&trans[kj][h0 * 8 + u4];
            *(float4*)&dstb[((size_t)h0 * 256 + kloc0 + kj) * 8 + u4] = val;
        }
    }
}

// ------------- Kernel B (fused): score + masked softmax + PV ----------------
// Block = 4 waves = 4 q rows; wave = one k-group (k = 64w+lane) for ALL 4 q
// (each ek octet loaded once per block -> 32 rcp + 64 fma per 2 b128 loads).
// q/wv live in LDS, read as b128 BROADCASTS (no scalar-load latency chain, no
// conflicts). k loads explicitly 2-deep software-pipelined. PV: 4-deep batched
// V loads, p broadcast via readlane, cross-wave O reduce through LDS.
__global__ __launch_bounds__(256, 4) void attn_kernel(const float* __restrict__ EQ,
                                                      const float* __restrict__ EKT,
                                                      const float* __restrict__ wv,
                                                      const int* __restrict__ lens,
                                                      const float* __restrict__ V,
                                                      float* __restrict__ OUT) {
    const int b = blockIdx.y;
    const int q0 = blockIdx.x * 4;
    const int len = lens[b];

    __shared__ float eq_lds[4][256];    // 4 KB
    __shared__ float wv_lds[256];       // 1 KB
    __shared__ float part[4][4][256];   // 16 KB
    __shared__ float maxb[4][4];
    __shared__ float sumb[4][4];

    const int tid = threadIdx.x;
    const int w = tid >> 6, lane = tid & 63;

    {
        int r = tid >> 6, c4 = (tid & 63) << 2;
        *(float4*)&eq_lds[r][c4] =
            *(const float4*)&EQ[((size_t)b * QN + q0 + r) * HN + c4];
        if (tid < 64) *(float4*)&wv_lds[tid << 2] = *(const float4*)&wv[tid << 2];
    }
    __syncthreads();

    const bool act = (w * 64) < len;          // wave-uniform
    float acc[4] = {0.f, 0.f, 0.f, 0.f};

#define WINDOW(KA, KB, H8)                                                        \
    do {                                                                          \
        float4 wa = *(const float4*)&wv_lds[(H8)];                                \
        float4 wb = *(const float4*)&wv_lds[(H8) + 4];                            \
        _Pragma("unroll") for (int qq = 0; qq < 4; ++qq) {                        \
            float4 qa = *(const float4*)&eq_lds[qq][(H8)];                        \
            float4 qb = *(const float4*)&eq_lds[qq][(H8) + 4];                    \
            float t = acc[qq];                                                    \
            t = fmaf(wa.x, __builtin_amdgcn_rcpf(fmaf(qa.x, KA.x, 1.f)), t);      \
            t = fmaf(wa.y, __builtin_amdgcn_rcpf(fmaf(qa.y, KA.y, 1.f)), t);      \
            t = fmaf(wa.z, __builtin_amdgcn_rcpf(fmaf(qa.z, KA.z, 1.f)), t);      \
            t = fmaf(wa.w, __builtin_amdgcn_rcpf(fmaf(qa.w, KA.w, 1.f)), t);      \
            t = fmaf(wb.x, __builtin_amdgcn_rcpf(fmaf(qb.x, KB.x, 1.f)), t);      \
            t = fmaf(wb.y, __builtin_amdgcn_rcpf(fmaf(qb.y, KB.y, 1.f)), t);      \
            t = fmaf(wb.z, __builtin_amdgcn_rcpf(fmaf(qb.z, KB.z, 1.f)), t);      \
            t = fmaf(wb.w, __builtin_amdgcn_rcpf(fmaf(qb.w, KB.w, 1.f)), t);      \
            acc[qq] = t;                                                          \
        }                                                                         \
    } while (0)

    if (act) {
        const float* kp = EKT + (size_t)b * (32 * 256 * 8) + (size_t)(w * 64 + lane) * 8;
        float4 ka0 = *(const float4*)&kp[0];
        float4 kb0 = *(const float4*)&kp[4];
        float4 ka1, kb1;
        for (int hw = 0; hw < 32; hw += 2) {
            const float* kp1 = kp + (size_t)(hw + 1) * 2048;
            ka1 = *(const float4*)&kp1[0];
            kb1 = *(const float4*)&kp1[4];
            WINDOW(ka0, kb0, hw * 8);
            if (hw + 2 < 32) {
                const float* kp2 = kp + (size_t)(hw + 2) * 2048;
                ka0 = *(const float4*)&kp2[0];
                kb0 = *(const float4*)&kp2[4];
            }
            WINDOW(ka1, kb1, hw * 8 + 8);
        }
    }

    const bool kvalid = (w * 64 + lane) < len;
    float xs0 = kvalid ? (-2.f * acc[0]) : -1e6f;
    float xs1 = kvalid ? (-2.f * acc[1]) : -1e6f;
    float xs2 = kvalid ? (-2.f * acc[2]) : -1e6f;
    float xs3 = kvalid ? (-2.f * acc[3]) : -1e6f;

    float m0 = xs0, m1 = xs1, m2 = xs2, m3 = xs3;
#pragma unroll
    for (int off = 32; off; off >>= 1) {
        m0 = fmaxf(m0, __shfl_xor(m0, off, 64));
        m1 = fmaxf(m1, __shfl_xor(m1, off, 64));
        m2 = fmaxf(m2, __shfl_xor(m2, off, 64));
        m3 = fmaxf(m3, __shfl_xor(m3, off, 64));
    }
    if (lane == 0) {
        maxb[w][0] = m0; maxb[w][1] = m1; maxb[w][2] = m2; maxb[w][3] = m3;
    }
    __syncthreads();
    float g0 = fmaxf(fmaxf(maxb[0][0], maxb[1][0]), fmaxf(maxb[2][0], maxb[3][0]));
    float g1 = fmaxf(fmaxf(maxb[0][1], maxb[1][1]), fmaxf(maxb[2][1], maxb[3][1]));
    float g2 = fmaxf(fmaxf(maxb[0][2], maxb[1][2]), fmaxf(maxb[2][2], maxb[3][2]));
    float g3 = fmaxf(fmaxf(maxb[0][3], maxb[1][3]), fmaxf(maxb[2][3], maxb[3][3]));

    float p0 = __builtin_amdgcn_exp2f((xs0 - g0) * LOG2E);
    float p1 = __builtin_amdgcn_exp2f((xs1 - g1) * LOG2E);
    float p2 = __builtin_amdgcn_exp2f((xs2 - g2) * LOG2E);
    float p3 = __builtin_amdgcn_exp2f((xs3 - g3) * LOG2E);

    float s0 = p0, s1 = p1, s2 = p2, s3 = p3;
#pragma unroll
    for (int off = 32; off; off >>= 1) {
        s0 += __shfl_xor(s0, off, 64);
        s1 += __shfl_xor(s1, off, 64);
        s2 += __shfl_xor(s2, off, 64);
        s3 += __shfl_xor(s3, off, 64);
    }
    if (lane == 0) {
        sumb[w][0] = s0; sumb[w][1] = s1; sumb[w][2] = s2; sumb[w][3] = s3;
    }
    __syncthreads();
    float t0 = (sumb[0][0] + sumb[1][0]) + (sumb[2][0] + sumb[3][0]);
    float t1 = (sumb[0][1] + sumb[1][1]) + (sumb[2][1] + sumb[3][1]);
    float t2 = (sumb[0][2] + sumb[1][2]) + (sumb[2][2] + sumb[3][2]);
    float t3 = (sumb[0][3] + sumb[1][3]) + (sumb[2][3] + sumb[3][3]);
    p0 *= 1.f / t0;
    p1 *= 1.f / t1;
    p2 *= 1.f / t2;
    p3 *= 1.f / t3;

    // PV: wave w covers its 64 k rows (clamped to len); 4-deep batched V loads
    float4 op0 = make_float4(0.f, 0.f, 0.f, 0.f);
    float4 op1 = op0, op2 = op0, op3 = op0;
    if (act) {
        int kmax = len - w * 64;
        if (kmax > 64) kmax = 64;
        const float* vb = V + ((size_t)b * KN + (size_t)w * 64) * DN + (lane << 2);

#define PV_STEP(KK, VV)                                                        \
    do {                                                                       \
        float b0 = readlane_f(p0, (KK));                                       \
        float b1 = readlane_f(p1, (KK));                                       \
        float b2 = readlane_f(p2, (KK));                                       \
        float b3 = readlane_f(p3, (KK));                                       \
        op0.x = fmaf(b0, VV.x, op0.x); op0.y = fmaf(b0, VV.y, op0.y);          \
        op0.z = fmaf(b0, VV.z, op0.z); op0.w = fmaf(b0, VV.w, op0.w);          \
        op1.x = fmaf(b1, VV.x, op1.x); op1.y = fmaf(b1, VV.y, op1.y);          \
        op1.z = fmaf(b1, VV.z, op1.z); op1.w = fmaf(b1, VV.w, op1.w);          \
        op2.x = fmaf(b2, VV.x, op2.x); op2.y = fmaf(b2, VV.y, op2.y);          \
        op2.z = fmaf(b2, VV.z, op2.z); op2.w = fmaf(b2, VV.w, op2.w);          \
        op3.x = fmaf(b3, VV.x, op3.x); op3.y = fmaf(b3, VV.y, op3.y);          \
        op3.z = fmaf(b3, VV.z, op3.z); op3.w = fmaf(b3, VV.w, op3.w);          \
    } while (0)

        int kk = 0;
        for (; kk + 4 <= kmax; kk += 4) {
            float4 v0 = *(const float4*)&vb[(size_t)(kk + 0) * DN];
            float4 v1 = *(const float4*)&vb[(size_t)(kk + 1) * DN];
            float4 v2 = *(const float4*)&vb[(size_t)(kk + 2) * DN];
            float4 v3 = *(const float4*)&vb[(size_t)(kk + 3) * DN];
            PV_STEP(kk + 0, v0);
            PV_STEP(kk + 1, v1);
            PV_STEP(kk + 2, v2);
            PV_STEP(kk + 3, v3);
        }
        for (; kk < kmax; ++kk) {
            float4 v0 = *(const float4*)&vb[(size_t)kk * DN];
            PV_STEP(kk, v0);
        }
    }
    {
        const int d4 = lane << 2;
        *(float4*)&part[w][0][d4] = op0;
        *(float4*)&part[w][1][d4] = op1;
        *(float4*)&part[w][2][d4] = op2;
        *(float4*)&part[w][3][d4] = op3;
    }
    __syncthreads();

    {
        const int q = tid >> 6, ln = tid & 63;
        const int d4 = ln << 2;
        float4 r0 = *(const float4*)&part[0][q][d4];
        float4 r1 = *(const float4*)&part[1][q][d4];
        float4 r2 = *(const float4*)&part[2][q][d4];
        float4 r3 = *(const float4*)&part[3][q][d4];
        float4 r = make_float4((r0.x + r1.x) + (r2.x + r3.x),
                               (r0.y + r1.y) + (r2.y + r3.y),
                               (r0.z + r1.z) + (r2.z + r3.z),
                               (r0.w + r1.w) + (r2.w + r3.w));
        *(float4*)&OUT[((size_t)b * QN + q0 + q) * DN + d4] = r;
    }
}

extern "C" void kernel_launch(void* const* d_in, const int* in_sizes, int n_in,
                              void* d_out, int out_size, void* d_ws, size_t ws_size,
                              hipStream_t stream) {
    const float* queries = (const float*)d_in[0];
    const float* keys    = (const float*)d_in[1];
    const float* values  = (const float*)d_in[2];
    const int*   lens    = (const int*)d_in[3];
    const float* Wq      = (const float*)d_in[4];
    const float* Wk      = (const float*)d_in[5];
    const float* wv      = (const float*)d_in[6];
    float* out = (float*)d_out;

    float* eq  = (float*)d_ws;                       // [B,Q,H]   4 MB (exp'd, row-major)
    float* ekT = eq + (size_t)B_ * QN * HN;          // [B,32,K,8] 4 MB (exp'd, octets)

    proj_kernel<<<(B_ * QN + B_ * KN) / 16, 256, 0, stream>>>(
        queries, keys, Wq, Wk, eq, ekT, TWOLOG2E);

    dim3 gB(QN / 4, B_);
    attn_kernel<<<gB, 256, 0, stream>>>(eq, ekT, wv, lens, values, out);
}